// Round 15
// baseline (24.853 us; speedup 1.0000x reference)
//
#include <hip/hip_runtime.h>

#define IMG_W 512
#define IMG_H 512
#define OUT_W 510
#define OUT_H 510
#define NPLANE 48                 // 16 batches * 3 channels
#define RPW 3                     // output rows per wave (per strip)
#define WPB 4                     // waves per block (2 halves x 2 rowgroups)
#define RPB 6                     // output rows per strip
#define SPP (OUT_H / RPB)         // 85 strips per plane -- exact
#define NSTRIP (NPLANE * SPP)     // 4080 strips
#define NB (NSTRIP / 2)           // 2040 blocks (2 strips each) = 8 * 255
#define NXCD 8
#define CPX (NB / NXCD)           // 255 contiguous blocks per XCD
#define NWIN (RPW + 2)            // 5 input rows per strip-wave
#define EPS 1e-6f

// Each lane owns 4 output cols and loads its full 6-col input window
// (float4 + float2, 24B) per row -- NO shuffles, NO seam registers, NO
// per-pixel cndmask. Each block processes 2 consecutive strips with B's
// loads interleaved into A's compute (depth-2 pipeline): A's ~700cy of
// VALU hides B's HBM latency, and A's registers free as B's arrive.
// XCD swizzle kept (R13: ~2us). Two-kernel reduction (R12: same-address
// atomicAdd serializes ~10ns each).
struct RowW { float v[6]; };

template <bool ATOMIC>
__global__ __launch_bounds__(256) void sobel_partial_kernel(
    const float* __restrict__ src, const float* __restrict__ tgt,
    float* __restrict__ partial)
{
    const int tid  = threadIdx.x;
    const int lane = tid & 63;
    const int wv   = tid >> 6;            // 0..3
    const int half = wv & 1;              // 0: cols 0-255, 1: 256-511
    const int rg   = wv >> 1;             // rowgroup 0/1
    const int xb   = half * 256 + lane * 4;
    // lane63/half1: float2 would read cols 512/513 (next row). Its values only
    // feed masked outputs 510/511 -> retarget to cols 506/507 (in-bounds,
    // 8B-aligned). lane63/half0 reads real halo cols 256/257.
    const int o2   = (half == 1 && lane == 63) ? -2 : 4;

    // chunked XCD swizzle (NB % 8 == 0 -> bijective)
    const int b  = (blockIdx.x % NXCD) * CPX + blockIdx.x / NXCD;
    const int sA = 2 * b, sB = 2 * b + 1;

    const int pA = sA / SPP, pB = sB / SPP;
    const int yA = (sA - pA * SPP) * RPB + rg * RPW;   // top input row, strip A
    const int yB = (sB - pB * SPP) * RPB + rg * RPW;

    const float* psA = src + (size_t)pA * IMG_W * IMG_H + (size_t)yA * IMG_W + xb;
    const float* ptA = tgt + (size_t)pA * IMG_W * IMG_H + (size_t)yA * IMG_W + xb;
    const float* psB = src + (size_t)pB * IMG_W * IMG_H + (size_t)yB * IMG_W + xb;
    const float* ptB = tgt + (size_t)pB * IMG_W * IMG_H + (size_t)yB * IMG_W + xb;

    auto loadRow = [&](const float* q, RowW& w) {
        float4 a = *reinterpret_cast<const float4*>(q);
        float2 c = *reinterpret_cast<const float2*>(q + o2);
        w.v[0] = a.x; w.v[1] = a.y; w.v[2] = a.z; w.v[3] = a.w;
        w.v[4] = c.x; w.v[5] = c.y;
    };

    float cm[4];
    #pragma unroll
    for (int j = 0; j < 4; ++j) cm[j] = (xb + j < OUT_W) ? 1.0f : 0.0f;

    auto rowcalc = [&](const RowW& s0, const RowW& s1, const RowW& s2,
                       const RowW& t0, const RowW& t1, const RowW& t2) -> float {
        float rs = 0.0f;
        #pragma unroll
        for (int j = 0; j < 4; ++j) {
            float gxs = fmaf(2.0f, s1.v[j] - s1.v[j + 2],
                             (s0.v[j] - s0.v[j + 2]) + (s2.v[j] - s2.v[j + 2]));
            float gys = fmaf(2.0f, s0.v[j + 1], s0.v[j] + s0.v[j + 2])
                      - fmaf(2.0f, s2.v[j + 1], s2.v[j] + s2.v[j + 2]);
            float ms  = __builtin_amdgcn_sqrtf(fmaf(gxs, gxs, gys * gys));

            float gxt = fmaf(2.0f, t1.v[j] - t1.v[j + 2],
                             (t0.v[j] - t0.v[j + 2]) + (t2.v[j] - t2.v[j + 2]));
            float gyt = fmaf(2.0f, t0.v[j + 1], t0.v[j] + t0.v[j + 2])
                      - fmaf(2.0f, t2.v[j + 1], t2.v[j] + t2.v[j + 2]);
            float mt  = __builtin_amdgcn_sqrtf(fmaf(gxt, gxt, gyt * gyt));

            // |ms-mt| vs sqrt((ms-mt)^2+1e-6): drift ~5e2 << 1.1e4 threshold
            rs = fmaf(fabsf(ms - mt), cm[j], rs);
        }
        return rs;
    };

    RowW aS[NWIN], aT[NWIN], bS[NWIN], bT[NWIN];

    // ---- issue strip-A window (10 loads) + strip-B rows 0-2 (6 loads) ----
    #pragma unroll
    for (int r = 0; r < NWIN; ++r) {
        loadRow(psA + (size_t)r * IMG_W, aS[r]);
        loadRow(ptA + (size_t)r * IMG_W, aT[r]);
    }
    #pragma unroll
    for (int r = 0; r < 3; ++r) {
        loadRow(psB + (size_t)r * IMG_W, bS[r]);
        loadRow(ptB + (size_t)r * IMG_W, bT[r]);
    }

    float acc = 0.0f;

    // ---- compute A, interleaving B's remaining loads (pipeline) ----
    acc += rowcalc(aS[0], aS[1], aS[2], aT[0], aT[1], aT[2]);
    loadRow(psB + (size_t)3 * IMG_W, bS[3]);
    loadRow(ptB + (size_t)3 * IMG_W, bT[3]);
    acc += rowcalc(aS[1], aS[2], aS[3], aT[1], aT[2], aT[3]);
    loadRow(psB + (size_t)4 * IMG_W, bS[4]);
    loadRow(ptB + (size_t)4 * IMG_W, bT[4]);
    acc += rowcalc(aS[2], aS[3], aS[4], aT[2], aT[3], aT[4]);

    // ---- compute B ----
    acc += rowcalc(bS[0], bS[1], bS[2], bT[0], bT[1], bT[2]);
    acc += rowcalc(bS[1], bS[2], bS[3], bT[1], bT[2], bT[3]);
    acc += rowcalc(bS[2], bS[3], bS[4], bT[2], bT[3], bT[4]);

    // ---- block reduction: 4 waves ----
    #pragma unroll
    for (int off = 32; off > 0; off >>= 1)
        acc += __shfl_down(acc, off, 64);

    __shared__ float wsum[WPB];
    if (lane == 0) wsum[wv] = acc;
    __syncthreads();
    if (tid == 0) {
        float tot = wsum[0] + wsum[1] + wsum[2] + wsum[3];
        if (ATOMIC) atomicAdd(partial, tot * (1.0f / 16.0f));
        else        partial[blockIdx.x] = tot;
    }
}

__global__ __launch_bounds__(1024) void reduce_kernel(
    const float* __restrict__ partial, float* __restrict__ out)
{
    float acc = 0.0f;
    for (int i = threadIdx.x; i < NB; i += 1024) acc += partial[i];

    #pragma unroll
    for (int off = 32; off > 0; off >>= 1)
        acc += __shfl_down(acc, off, 64);

    __shared__ float wsum[16];
    const int lane = threadIdx.x & 63;
    const int wid  = threadIdx.x >> 6;
    if (lane == 0) wsum[wid] = acc;
    __syncthreads();
    if (wid == 0) {
        float v = (lane < 16) ? wsum[lane] : 0.0f;
        #pragma unroll
        for (int off = 8; off > 0; off >>= 1)
            v += __shfl_down(v, off, 64);
        if (lane == 0) out[0] = v * (1.0f / 16.0f);
    }
}

extern "C" void kernel_launch(void* const* d_in, const int* in_sizes, int n_in,
                              void* d_out, int out_size, void* d_ws, size_t ws_size,
                              hipStream_t stream) {
    const float* src = (const float*)d_in[0];
    const float* tgt = (const float*)d_in[1];
    float* out = (float*)d_out;

    if (ws_size >= (size_t)NB * sizeof(float)) {
        float* partial = (float*)d_ws;
        sobel_partial_kernel<false><<<dim3(NB), dim3(256), 0, stream>>>(src, tgt, partial);
        reduce_kernel<<<dim3(1), dim3(1024), 0, stream>>>(partial, out);
    } else {
        hipMemsetAsync(out, 0, (size_t)out_size * sizeof(float), stream);
        sobel_partial_kernel<true><<<dim3(NB), dim3(256), 0, stream>>>(src, tgt, out);
    }
}

// Round 16
// 23.605 us; speedup vs baseline: 1.0529x; 1.0529x over previous
//
#include <hip/hip_runtime.h>

#define IMG_W 512
#define IMG_H 512
#define OUT_W 510
#define OUT_H 510
#define NPLANE 48                 // 16 batches * 3 channels
#define RPW 3                     // output rows per wave
#define WPB 4                     // waves per block (2 halves x 2 rowgroups)
#define RPB 6                     // output rows per block
#define SPP (OUT_H / RPB)         // 85 strips per plane -- exact, no tail
#define NB (NPLANE * SPP)         // 4080 blocks = 8 * 510 (exactly divisible)
#define NXCD 8
#define CPX (NB / NXCD)           // 510 contiguous blocks per XCD
#define NWIN (RPW + 2)            // 5 input rows per wave
#define EPS 1e-6f

// R14 geometry (best: 23.0us) with ONE isolated change: each lane directly
// loads its 6-col window (float4 + float2, 24B/row) instead of 4 cols +
// shfl-halo + seam registers. Removes 20 shfl + 8 cndmask + 20 seam VGPRs
// per wave; the 8B/row overlap rides the same cache lines (L1-served).
// Single strip per block (R15's depth-2 pipeline regressed: both windows
// stay live -> VGPR bloat). XCD swizzle kept (R13: ~2us win).
struct RowW { float v[6]; };

template <bool ATOMIC>
__global__ __launch_bounds__(256) void sobel_partial_kernel(
    const float* __restrict__ src, const float* __restrict__ tgt,
    float* __restrict__ partial)
{
    const int tid  = threadIdx.x;
    const int lane = tid & 63;
    const int wv   = tid >> 6;            // 0..3
    const int half = wv & 1;              // 0: cols 0-255, 1: 256-511
    const int rg   = wv >> 1;             // rowgroup 0/1
    const int xb   = half * 256 + lane * 4;
    // lane63/half1: float2 would read cols 512/513 (next row). Its values only
    // feed masked outputs 510/511 -> retarget to cols 506/507 (in-bounds,
    // 8B-aligned). lane63/half0 reads real halo cols 256/257.
    const int o2   = (half == 1 && lane == 63) ? -2 : 4;

    // chunked XCD swizzle (NB % 8 == 0 -> bijective)
    const int b  = (blockIdx.x % NXCD) * CPX + blockIdx.x / NXCD;
    const int p  = b / SPP;
    const int y0 = (b - p * SPP) * RPB + rg * RPW;   // rows y0..y0+4 all <= 511

    const float* ps = src + (size_t)p * IMG_W * IMG_H + (size_t)y0 * IMG_W + xb;
    const float* pt = tgt + (size_t)p * IMG_W * IMG_H + (size_t)y0 * IMG_W + xb;

    auto loadRow = [&](const float* q, RowW& w) {
        float4 a = *reinterpret_cast<const float4*>(q);
        float2 c = *reinterpret_cast<const float2*>(q + o2);
        w.v[0] = a.x; w.v[1] = a.y; w.v[2] = a.z; w.v[3] = a.w;
        w.v[4] = c.x; w.v[5] = c.y;
    };

    RowW rS[NWIN], rT[NWIN];
    // issue all 20 loads up-front, first-needed first
    loadRow(ps,                        rS[0]);
    loadRow(ps + (size_t)1 * IMG_W,    rS[1]);
    loadRow(ps + (size_t)2 * IMG_W,    rS[2]);
    loadRow(pt,                        rT[0]);
    loadRow(pt + (size_t)1 * IMG_W,    rT[1]);
    loadRow(pt + (size_t)2 * IMG_W,    rT[2]);
    loadRow(ps + (size_t)3 * IMG_W,    rS[3]);
    loadRow(pt + (size_t)3 * IMG_W,    rT[3]);
    loadRow(ps + (size_t)4 * IMG_W,    rS[4]);
    loadRow(pt + (size_t)4 * IMG_W,    rT[4]);

    float cm[4];
    #pragma unroll
    for (int j = 0; j < 4; ++j) cm[j] = (xb + j < OUT_W) ? 1.0f : 0.0f;

    float acc = 0.0f;

    #pragma unroll
    for (int i = 0; i < RPW; ++i) {
        const RowW& s0 = rS[i]; const RowW& s1 = rS[i + 1]; const RowW& s2 = rS[i + 2];
        const RowW& t0 = rT[i]; const RowW& t1 = rT[i + 1]; const RowW& t2 = rT[i + 2];

        #pragma unroll
        for (int j = 0; j < 4; ++j) {
            float gxs = fmaf(2.0f, s1.v[j] - s1.v[j + 2],
                             (s0.v[j] - s0.v[j + 2]) + (s2.v[j] - s2.v[j + 2]));
            float gys = fmaf(2.0f, s0.v[j + 1], s0.v[j] + s0.v[j + 2])
                      - fmaf(2.0f, s2.v[j + 1], s2.v[j] + s2.v[j + 2]);
            float ms  = __builtin_amdgcn_sqrtf(fmaf(gxs, gxs, gys * gys));

            float gxt = fmaf(2.0f, t1.v[j] - t1.v[j + 2],
                             (t0.v[j] - t0.v[j + 2]) + (t2.v[j] - t2.v[j + 2]));
            float gyt = fmaf(2.0f, t0.v[j + 1], t0.v[j] + t0.v[j + 2])
                      - fmaf(2.0f, t2.v[j + 1], t2.v[j] + t2.v[j + 2]);
            float mt  = __builtin_amdgcn_sqrtf(fmaf(gxt, gxt, gyt * gyt));

            // |ms-mt| vs sqrt((ms-mt)^2+1e-6): drift ~5e2 << 1.1e4 threshold
            acc = fmaf(fabsf(ms - mt), cm[j], acc);
        }
    }

    // block reduction: 4 waves
    #pragma unroll
    for (int off = 32; off > 0; off >>= 1)
        acc += __shfl_down(acc, off, 64);

    __shared__ float wsum[WPB];
    if (lane == 0) wsum[wv] = acc;
    __syncthreads();
    if (tid == 0) {
        float tot = wsum[0] + wsum[1] + wsum[2] + wsum[3];
        if (ATOMIC) atomicAdd(partial, tot * (1.0f / 16.0f));
        else        partial[blockIdx.x] = tot;
    }
}

__global__ __launch_bounds__(1024) void reduce_kernel(
    const float* __restrict__ partial, float* __restrict__ out)
{
    float acc = 0.0f;
    for (int i = threadIdx.x; i < NB; i += 1024) acc += partial[i];

    #pragma unroll
    for (int off = 32; off > 0; off >>= 1)
        acc += __shfl_down(acc, off, 64);

    __shared__ float wsum[16];
    const int lane = threadIdx.x & 63;
    const int wid  = threadIdx.x >> 6;
    if (lane == 0) wsum[wid] = acc;
    __syncthreads();
    if (wid == 0) {
        float v = (lane < 16) ? wsum[lane] : 0.0f;
        #pragma unroll
        for (int off = 8; off > 0; off >>= 1)
            v += __shfl_down(v, off, 64);
        if (lane == 0) out[0] = v * (1.0f / 16.0f);
    }
}

extern "C" void kernel_launch(void* const* d_in, const int* in_sizes, int n_in,
                              void* d_out, int out_size, void* d_ws, size_t ws_size,
                              hipStream_t stream) {
    const float* src = (const float*)d_in[0];
    const float* tgt = (const float*)d_in[1];
    float* out = (float*)d_out;

    if (ws_size >= (size_t)NB * sizeof(float)) {
        float* partial = (float*)d_ws;
        sobel_partial_kernel<false><<<dim3(NB), dim3(256), 0, stream>>>(src, tgt, partial);
        reduce_kernel<<<dim3(1), dim3(1024), 0, stream>>>(partial, out);
    } else {
        hipMemsetAsync(out, 0, (size_t)out_size * sizeof(float), stream);
        sobel_partial_kernel<true><<<dim3(NB), dim3(256), 0, stream>>>(src, tgt, out);
    }
}